// Round 2
// baseline (51.064 us; speedup 1.0000x reference)
//
#include <hip/hip_runtime.h>

// One-way Chamfer (L1, K=1): out[0] = mean_i min_j ||x_i - y_j||_1 ; out[1..N] = 0
// N = M = 16384, D = 3, fp32.
//
// Key idea this round: y-points are wave-uniform in the inner loop, so read
// them through the SCALAR path (s_load -> SGPR operand in VALU) instead of
// broadcasting through the LDS return bus (ds_read_b128 ~12cyc/wave was the
// R1 bottleneck: 2.1e6 reads * 12 / 256 CU = 41 us = measured duration).

#define TPB 256
#define RB 4                         // x-points per thread
#define PTS_PER_BLOCK (TPB * RB)     // 1024
#define MSEG 256                     // y-points per block (M split 64-way)

__global__ __launch_bounds__(TPB) void chamfer_kernel(
    const float* __restrict__ pc1, const float* __restrict__ flow,
    const float* __restrict__ pc2, unsigned* __restrict__ minbits,
    int N, int M) {
    const int t = threadIdx.x;
    const int ibase = blockIdx.x * PTS_PER_BLOCK + t;

    // load + deform this thread's 4 x-points
    float ax[RB], ay[RB], az[RB];
    bool valid[RB];
#pragma unroll
    for (int r = 0; r < RB; ++r) {
        int i = ibase + r * TPB;
        valid[r] = (i < N);
        int ic = valid[r] ? i : (N - 1);
        ax[r] = pc1[3 * ic]     + flow[3 * ic];
        ay[r] = pc1[3 * ic + 1] + flow[3 * ic + 1];
        az[r] = pc1[3 * ic + 2] + flow[3 * ic + 2];
    }

    const int y0 = blockIdx.y * MSEG;
    const int len = (M - y0 < MSEG) ? (M - y0) : MSEG;
    const float* __restrict__ ys = pc2 + (size_t)3 * (size_t)y0;  // uniform base

    float m[RB];
#pragma unroll
    for (int r = 0; r < RB; ++r) m[r] = 3.0e38f;

    if (len == MSEG) {
        // fast path: uniform scalar loads, 2 y per body, unroll x4 (8 y / iter)
#pragma unroll 4
        for (int j = 0; j < MSEG; j += 2) {
            const float y0x = ys[3 * j + 0], y0y = ys[3 * j + 1], y0z = ys[3 * j + 2];
            const float y1x = ys[3 * j + 3], y1y = ys[3 * j + 4], y1z = ys[3 * j + 5];
#pragma unroll
            for (int r = 0; r < RB; ++r) {
                const float d0 = fabsf(ax[r] - y0x) + fabsf(ay[r] - y0y) + fabsf(az[r] - y0z);
                const float d1 = fabsf(ax[r] - y1x) + fabsf(ay[r] - y1y) + fabsf(az[r] - y1z);
                m[r] = fminf(fminf(m[r], d0), d1);   // -> v_min3_f32
            }
        }
    } else {
        for (int j = 0; j < len; ++j) {
            const float yx = ys[3 * j + 0], yy = ys[3 * j + 1], yz = ys[3 * j + 2];
#pragma unroll
            for (int r = 0; r < RB; ++r) {
                const float d = fabsf(ax[r] - yx) + fabsf(ay[r] - yy) + fabsf(az[r] - yz);
                m[r] = fminf(m[r], d);
            }
        }
    }

    // exact, order-independent combine: uint atomicMin on nonneg float bits
#pragma unroll
    for (int r = 0; r < RB; ++r) {
        if (valid[r]) atomicMin(&minbits[ibase + r * TPB], __float_as_uint(m[r]));
    }
}

// single-block deterministic reduction: out[0] = sum(min) / N
__global__ __launch_bounds__(1024) void reduce_kernel(
    const unsigned* __restrict__ minbits, float* __restrict__ out, int N) {
    float s = 0.0f;
    const uint4* p = (const uint4*)minbits;
    for (int k = threadIdx.x; k < N / 4; k += 1024) {
        uint4 v = p[k];
        s += __uint_as_float(v.x) + __uint_as_float(v.y) +
             __uint_as_float(v.z) + __uint_as_float(v.w);
    }
    // handle N not multiple of 4 (not hit for N=16384)
    for (int k = (N / 4) * 4 + threadIdx.x; k < N; k += 1024)
        s += __uint_as_float(minbits[k]);
#pragma unroll
    for (int off = 32; off > 0; off >>= 1) s += __shfl_down(s, off, 64);
    __shared__ float ls[16];
    const int wid = threadIdx.x >> 6, lane = threadIdx.x & 63;
    if (lane == 0) ls[wid] = s;
    __syncthreads();
    if (threadIdx.x == 0) {
        float tot = 0.0f;
        for (int w = 0; w < 16; ++w) tot += ls[w];
        out[0] = tot / (float)N;
    }
}

extern "C" void kernel_launch(void* const* d_in, const int* in_sizes, int n_in,
                              void* d_out, int out_size, void* d_ws, size_t ws_size,
                              hipStream_t stream) {
    const float* pc1  = (const float*)d_in[0];
    const float* flow = (const float*)d_in[1];
    const float* pc2  = (const float*)d_in[2];
    float* out = (float*)d_out;

    const int N = in_sizes[0] / 3;
    const int M = in_sizes[2] / 3;

    unsigned* minbits = (unsigned*)d_ws;

    // freespace_loss part of d_out stays zero; out[0] overwritten by reduce
    hipMemsetAsync(d_out, 0, (size_t)out_size * sizeof(float), stream);
    // 0x7F7F7F7F = 3.39e38f: valid "infinity" sentinel, uint order == float
    // order for nonnegative floats, and settable by byte-pattern memset.
    hipMemsetAsync(minbits, 0x7F, (size_t)N * sizeof(unsigned), stream);

    const int nbN    = (N + PTS_PER_BLOCK - 1) / PTS_PER_BLOCK;  // 16
    const int msplit = (M + MSEG - 1) / MSEG;                    // 64

    chamfer_kernel<<<dim3(nbN, msplit), TPB, 0, stream>>>(pc1, flow, pc2, minbits, N, M);
    reduce_kernel<<<1, 1024, 0, stream>>>(minbits, out, N);
}